// Round 1
// baseline (225.886 us; speedup 1.0000x reference)
//
#include <hip/hip_runtime.h>
#include <math.h>

#define NB 32
#define KK 2
#define PP 256
#define NCLOUD 8192
#define NNODES 512   // K*P
#define NCOEF 163840 // B*K*P*COEF_D

__device__ inline float waveSum(float v) {
#pragma unroll
  for (int o = 32; o > 0; o >>= 1) v += __shfl_down(v, o);
  return v;
}
__device__ inline float waveMax(float v) {
#pragma unroll
  for (int o = 32; o > 0; o >>= 1) v = fmaxf(v, __shfl_down(v, o));
  return v;
}
__device__ inline float waveMin(float v) {
#pragma unroll
  for (int o = 32; o > 0; o >>= 1) v = fminf(v, __shfl_down(v, o));
  return v;
}
__device__ inline float smooth_l1(float d) {
  d = fabsf(d);
  return d < 0.1f ? 5.0f * d * d : d - 0.05f;
}

// ---------------- chamfer + separation: one block per (b,k) ----------------
__global__ __launch_bounds__(256) void chamfer_sep_kernel(
    const float* __restrict__ preds,   // (B,K,P,3)
    const float* __restrict__ nodes,   // (B,K,P,3)
    const float* __restrict__ scale,   // (B,K,3)
    float* __restrict__ ws) {
  const int bk = blockIdx.x;           // b*K + k
  const int t = threadIdx.x;           // 0..255
  __shared__ float spx[PP], spy[PP], spz[PP];
  __shared__ float snx[PP], sny[PP], snz[PP];
  const float* pb = preds + (size_t)bk * PP * 3;
  const float* nb = nodes + (size_t)bk * PP * 3;
  spx[t] = pb[t * 3 + 0]; spy[t] = pb[t * 3 + 1]; spz[t] = pb[t * 3 + 2];
  snx[t] = nb[t * 3 + 0]; sny[t] = nb[t * 3 + 1]; snz[t] = nb[t * 3 + 2];
  __syncthreads();
  const float s0 = scale[bk * 3 + 0], s1 = scale[bk * 3 + 1], s2 = scale[bk * 3 + 2];
  const float thr = sqrtf(s0 * s0 + s1 * s1 + s2 * s2) * 0.125f;
  const float px = spx[t], py = spy[t], pz = spz[t];
  const float nx = snx[t], ny = sny[t], nz = snz[t];
  float m1 = 1e30f, m2 = 1e30f, sep = 0.0f;
  for (int j = 0; j < PP; ++j) {
    const float ax = snx[j], ay = sny[j], az = snz[j];
    float dx = px - ax, dy = py - ay, dz = pz - az;
    m1 = fminf(m1, dx * dx + dy * dy + dz * dz);
    const float bx = spx[j], by = spy[j], bz = spz[j];
    dx = nx - bx; dy = ny - by; dz = nz - bz;
    m2 = fminf(m2, dx * dx + dy * dy + dz * dz);
    dx = nx - ax; dy = ny - ay; dz = nz - az;
    const float d3 = sqrtf(dx * dx + dy * dy + dz * dz);
    const float rel = thr - d3;
    if (j != t && rel > 0.0f) sep += rel;
  }
  float chf = sqrtf(fmaxf(m1, 1e-12f)) + sqrtf(fmaxf(m2, 1e-12f));
  chf = waveSum(chf);
  sep = waveSum(sep);
  __shared__ float rc[4], rs[4];
  const int wave = t >> 6, lane = t & 63;
  if (lane == 0) { rc[wave] = chf; rs[wave] = sep; }
  __syncthreads();
  if (t == 0) {
    atomicAdd(&ws[0], rc[0] + rc[1] + rc[2] + rc[3]);
    atomicAdd(&ws[1], rs[0] + rs[1] + rs[2] + rs[3]);
  }
}

// ---------------- surface loss: block = (node-chunk of 64, b) ----------------
__global__ __launch_bounds__(256) void surf_kernel(
    const float* __restrict__ nodes,   // (B, 512, 3)
    const float* __restrict__ cloud,   // (B, 8192, 3)
    float* __restrict__ ws) {
  const int b = blockIdx.y;
  const int chunk = blockIdx.x;        // 0..7
  const int t = threadIdx.x;
  const int nl = t & 63;               // local node
  const int slice = t >> 6;            // 0..3 slice of cloud tile
  const int node = chunk * 64 + nl;
  const float* np_ = nodes + ((size_t)b * NNODES + node) * 3;
  const float px = np_[0], py = np_[1], pz = np_[2];
  __shared__ float raw[768];           // 256 points interleaved xyz
  __shared__ float smin[256];
  float m = 1e30f;
  const float* cb = cloud + (size_t)b * NCLOUD * 3;
  for (int f0 = 0; f0 < NCLOUD * 3; f0 += 768) {
    raw[t] = cb[f0 + t];
    raw[t + 256] = cb[f0 + t + 256];
    raw[t + 512] = cb[f0 + t + 512];
    __syncthreads();
    const int p0 = slice * 64 * 3;
#pragma unroll 16
    for (int p = 0; p < 64; ++p) {
      const float dx = px - raw[p0 + p * 3 + 0];
      const float dy = py - raw[p0 + p * 3 + 1];
      const float dz = pz - raw[p0 + p * 3 + 2];
      m = fminf(m, dx * dx + dy * dy + dz * dz);
    }
    __syncthreads();
  }
  smin[t] = m;
  __syncthreads();
  if (t < 64) {
    const float mm = fminf(fminf(smin[t], smin[t + 64]),
                           fminf(smin[t + 128], smin[t + 192]));
    float contrib = sqrtf(fmaxf(mm, 1e-12f));
    contrib = waveSum(contrib);
    if (t == 0) atomicAdd(&ws[2], contrib);
  }
}

// ---------------- coverage loss: one block per (b,k) ----------------
__global__ __launch_bounds__(256) void cov_kernel(
    const float* __restrict__ nodes,   // (B,K,P,3)
    const float* __restrict__ cloud,   // (B,N,3)
    const int* __restrict__ cls,       // (B,N)
    float* __restrict__ ws) {
  const int b = blockIdx.x >> 1;
  const int k = blockIdx.x & 1;
  const int t = threadIdx.x;
  float pmax0 = -1e9f, pmax1 = -1e9f, pmax2 = -1e9f;
  float pmin0 = 1e9f, pmin1 = 1e9f, pmin2 = 1e9f;
  const float* cb = cloud + (size_t)b * NCLOUD * 3;
  const int* lb = cls + (size_t)b * NCLOUD;
  for (int i = t; i < NCLOUD; i += 256) {
    if (lb[i] == k) {
      const float x = cb[i * 3 + 0], y = cb[i * 3 + 1], z = cb[i * 3 + 2];
      pmax0 = fmaxf(pmax0, x); pmax1 = fmaxf(pmax1, y); pmax2 = fmaxf(pmax2, z);
      pmin0 = fminf(pmin0, x); pmin1 = fminf(pmin1, y); pmin2 = fminf(pmin2, z);
    }
  }
  const float* nb = nodes + (size_t)(b * KK + k) * PP * 3;
  const float kx = nb[t * 3 + 0], ky = nb[t * 3 + 1], kz = nb[t * 3 + 2];

  pmax0 = waveMax(pmax0); pmax1 = waveMax(pmax1); pmax2 = waveMax(pmax2);
  pmin0 = waveMin(pmin0); pmin1 = waveMin(pmin1); pmin2 = waveMin(pmin2);
  float kmax0 = waveMax(kx), kmax1 = waveMax(ky), kmax2 = waveMax(kz);
  float kmin0 = waveMin(kx), kmin1 = waveMin(ky), kmin2 = waveMin(kz);

  __shared__ float red[12][4];
  const int wave = t >> 6, lane = t & 63;
  if (lane == 0) {
    red[0][wave] = pmax0; red[1][wave] = pmax1; red[2][wave] = pmax2;
    red[3][wave] = pmin0; red[4][wave] = pmin1; red[5][wave] = pmin2;
    red[6][wave] = kmax0; red[7][wave] = kmax1; red[8][wave] = kmax2;
    red[9][wave] = kmin0; red[10][wave] = kmin1; red[11][wave] = kmin2;
  }
  __syncthreads();
  if (t == 0) {
    float v[12];
#pragma unroll
    for (int q = 0; q < 12; ++q) {
      if (q < 3 || (q >= 6 && q < 9))
        v[q] = fmaxf(fmaxf(red[q][0], red[q][1]), fmaxf(red[q][2], red[q][3]));
      else
        v[q] = fminf(fminf(red[q][0], red[q][1]), fminf(red[q][2], red[q][3]));
    }
    float s = 0.0f;
#pragma unroll
    for (int c = 0; c < 3; ++c) {
      s += 0.5f * (smooth_l1(v[6 + c] - v[0 + c]) + smooth_l1(v[9 + c] - v[3 + c]));
    }
    atomicAdd(&ws[3], s);
  }
}

// ---------------- regularizer ----------------
__global__ __launch_bounds__(256) void reg_kernel(
    const float* __restrict__ coefs, float* __restrict__ ws) {
  float v = 0.0f;
  for (int i = blockIdx.x * 256 + threadIdx.x; i < NCOEF; i += gridDim.x * 256) {
    const float c = coefs[i];
    v += c * c;
  }
  v = waveSum(v);
  __shared__ float r[4];
  const int wave = threadIdx.x >> 6, lane = threadIdx.x & 63;
  if (lane == 0) r[wave] = v;
  __syncthreads();
  if (threadIdx.x == 0) atomicAdd(&ws[6], r[0] + r[1] + r[2] + r[3]);
}

// ---------------- joint loss: one block, 64 threads ----------------
__global__ __launch_bounds__(64) void joint_kernel(
    const float* __restrict__ pjl, const float* __restrict__ pja,
    const float* __restrict__ gjl, const float* __restrict__ gja,
    float* __restrict__ ws) {
  const int t = threadIdx.x;
  float cosv = 0.0f, locv = 0.0f;
  if (t < NB) {  // (K-1)=1 joint per batch
    const float ax = pja[t * 3 + 0], ay = pja[t * 3 + 1], az = pja[t * 3 + 2];
    const float gx = gja[t * 3 + 0], gy = gja[t * 3 + 1], gz = gja[t * 3 + 2];
    const float dot = ax * gx + ay * gy + az * gz;
    const float na = sqrtf(ax * ax + ay * ay + az * az);
    const float nbn = sqrtf(gx * gx + gy * gy + gz * gz);
    cosv = dot / fmaxf(na * nbn, 1e-8f);

    const float gn = sqrtf(gx * gx + gy * gy + gz * gz);
    const float ux = gx / gn, uy = gy / gn, uz = gz / gn;  // ngt
    const float px = gjl[t * 3 + 0], py = gjl[t * 3 + 1], pz = gjl[t * 3 + 2];
    const float qx = px + ux, qy = py + uy, qz = pz + uz;
    const float rx = pjl[t * 3 + 0], ry = pjl[t * 3 + 1], rz = pjl[t * 3 + 2];
    const float xx = px - qx, xy = py - qy, xz = pz - qz;  // = -u
    const float tnum = (rx - qx) * xx + (ry - qy) * xy + (rz - qz) * xz;
    const float tden = xx * xx + xy * xy + xz * xz;
    const float tv = tnum / tden;
    const float vx = tv * xx + (qx - rx);
    const float vy = tv * xy + (qy - ry);
    const float vz = tv * xz + (qz - rz);
    locv = sqrtf(vx * vx + vy * vy + vz * vz);
  }
  cosv = waveSum(cosv);
  locv = waveSum(locv);
  if (t == 0) {
    atomicAdd(&ws[4], cosv);
    atomicAdd(&ws[5], locv);
  }
}

// ---------------- final combine ----------------
__global__ void final_kernel(const float* __restrict__ ws, float* __restrict__ out) {
  const float chf = ws[0] / (float)(KK * NB * PP);
  const float sep = ws[1] / (float)(NB * KK * PP * (PP - 1));
  const float surf = ws[2] / (float)(NB * NNODES);
  const float cov = ws[3] / (float)(NB * KK * 3);
  const float axis = 1.0f - ws[4] / (float)NB;
  const float loc = ws[5] / (float)NB;
  const float joint = loc * 1.0f + axis * 0.5f;
  const float reg = ws[6] / (float)NCOEF;
  out[0] = chf * 1.0f + cov * 1.0f + surf * 5.0f + joint * 1.0f +
           reg * 0.01f + sep * 2.0f;
}

extern "C" void kernel_launch(void* const* d_in, const int* in_sizes, int n_in,
                              void* d_out, int out_size, void* d_ws, size_t ws_size,
                              hipStream_t stream) {
  const float* coefs = (const float*)d_in[0];
  const float* preds = (const float*)d_in[1];
  const float* nodes = (const float*)d_in[2];
  const float* cloud = (const float*)d_in[3];
  const int* cls = (const int*)d_in[4];
  const float* pjl = (const float*)d_in[5];
  const float* pja = (const float*)d_in[6];
  const float* gjl = (const float*)d_in[7];
  const float* gja = (const float*)d_in[8];
  const float* gps = (const float*)d_in[9];
  float* out = (float*)d_out;
  float* ws = (float*)d_ws;

  hipMemsetAsync(ws, 0, 8 * sizeof(float), stream);
  chamfer_sep_kernel<<<NB * KK, 256, 0, stream>>>(preds, nodes, gps, ws);
  surf_kernel<<<dim3(8, NB), 256, 0, stream>>>(nodes, cloud, ws);
  cov_kernel<<<NB * KK, 256, 0, stream>>>(nodes, cloud, cls, ws);
  reg_kernel<<<64, 256, 0, stream>>>(coefs, ws);
  joint_kernel<<<1, 64, 0, stream>>>(pjl, pja, gjl, gja, ws);
  final_kernel<<<1, 1, 0, stream>>>(ws, out);
}

// Round 2
// 61.645 us; speedup vs baseline: 3.6643x; 3.6643x over previous
//
#include <hip/hip_runtime.h>
#include <math.h>

#define NB 32
#define KK 2
#define PP 256
#define NCLOUD 8192
#define NNODES 512   // K*P
#define NCOEF 163840 // B*K*P*COEF_D

__device__ inline float waveSum(float v) {
#pragma unroll
  for (int o = 32; o > 0; o >>= 1) v += __shfl_down(v, o);
  return v;
}
__device__ inline float waveMax(float v) {
#pragma unroll
  for (int o = 32; o > 0; o >>= 1) v = fmaxf(v, __shfl_down(v, o));
  return v;
}
__device__ inline float waveMin(float v) {
#pragma unroll
  for (int o = 32; o > 0; o >>= 1) v = fminf(v, __shfl_down(v, o));
  return v;
}
__device__ inline float smooth_l1(float d) {
  d = fabsf(d);
  return d < 0.1f ? 5.0f * d * d : d - 0.05f;
}

// Block roles:
//   [0,512)    surf      : (b = bid&31, cloud chunk c = bid>>5 of 512 pts)
//   [512,576)  chamfer+sep per (b,k)
//   [576,640)  coverage  per (b,k)
//   [640,704)  regularizer (grid-stride)
//   704        joint
__global__ __launch_bounds__(256) void mega_kernel(
    const float* __restrict__ coefs,
    const float* __restrict__ preds,
    const float* __restrict__ nodes,
    const float* __restrict__ cloud,
    const int* __restrict__ cls,
    const float* __restrict__ pjl, const float* __restrict__ pja,
    const float* __restrict__ gjl, const float* __restrict__ gja,
    const float* __restrict__ gps,
    float* __restrict__ ws, unsigned int* __restrict__ minarr) {
  const int bid = blockIdx.x;
  const int t = threadIdx.x;
  __shared__ float sh[1536];
  __shared__ float red[12][4];
  const int wave = t >> 6, lane = t & 63;

  if (bid < 512) {
    // ---------------- surface loss (partial, per cloud chunk) ----------------
    const int c = bid >> 5;          // 0..15
    const int b = bid & 31;
    const float* cb = cloud + ((size_t)b * NCLOUD + c * 512) * 3;
    for (int i = t; i < 1536; i += 256) sh[i] = cb[i];
    __syncthreads();
    const float* nb = nodes + (size_t)b * NNODES * 3;
    const float ax = nb[t * 3 + 0], ay = nb[t * 3 + 1], az = nb[t * 3 + 2];
    const float bx = nb[(t + 256) * 3 + 0], by = nb[(t + 256) * 3 + 1],
                bz = nb[(t + 256) * 3 + 2];
    float m0a = 1e30f, m0b = 1e30f, m1a = 1e30f, m1b = 1e30f;
#define SURF_STEP(QX, QY, QZ, MA, MB_)                      \
  {                                                         \
    float dx = ax - (QX), dy = ay - (QY), dz = az - (QZ);   \
    MA = fminf(MA, dx * dx + dy * dy + dz * dz);            \
    dx = bx - (QX); dy = by - (QY); dz = bz - (QZ);         \
    MB_ = fminf(MB_, dx * dx + dy * dy + dz * dz);          \
  }
    for (int g = 0; g < 128; ++g) {
      const float4 q0 = *(const float4*)&sh[g * 12];
      const float4 q1 = *(const float4*)&sh[g * 12 + 4];
      const float4 q2 = *(const float4*)&sh[g * 12 + 8];
      SURF_STEP(q0.x, q0.y, q0.z, m0a, m1a);
      SURF_STEP(q0.w, q1.x, q1.y, m0b, m1b);
      SURF_STEP(q1.z, q1.w, q2.x, m0a, m1a);
      SURF_STEP(q2.y, q2.z, q2.w, m0b, m1b);
    }
#undef SURF_STEP
    atomicMin(&minarr[b * NNODES + t], __float_as_uint(fminf(m0a, m0b)));
    atomicMin(&minarr[b * NNODES + 256 + t], __float_as_uint(fminf(m1a, m1b)));

  } else if (bid < 576) {
    // ---------------- chamfer + separation per (b,k) ----------------
    const int bk = bid - 512;
    const float* pb = preds + (size_t)bk * PP * 3;
    const float* nbp = nodes + (size_t)bk * PP * 3;
    for (int i = t; i < 768; i += 256) { sh[i] = pb[i]; sh[768 + i] = nbp[i]; }
    __syncthreads();
    const float s0 = gps[bk * 3 + 0], s1 = gps[bk * 3 + 1], s2 = gps[bk * 3 + 2];
    const float thr = sqrtf(s0 * s0 + s1 * s1 + s2 * s2) * 0.125f;
    const float px = sh[t * 3 + 0], py = sh[t * 3 + 1], pz = sh[t * 3 + 2];
    const float nx = sh[768 + t * 3 + 0], ny = sh[768 + t * 3 + 1],
                nz = sh[768 + t * 3 + 2];
    float m1 = 1e30f, m2 = 1e30f, sep = 0.0f;
#define CHAM_STEP(JX, NXJ, NYJ, NZJ, PXJ, PYJ, PZJ)               \
  {                                                               \
    float dx = px - (NXJ), dy = py - (NYJ), dz = pz - (NZJ);      \
    m1 = fminf(m1, dx * dx + dy * dy + dz * dz);                  \
    dx = nx - (PXJ); dy = ny - (PYJ); dz = nz - (PZJ);            \
    m2 = fminf(m2, dx * dx + dy * dy + dz * dz);                  \
    dx = nx - (NXJ); dy = ny - (NYJ); dz = nz - (NZJ);            \
    float d3 = sqrtf(dx * dx + dy * dy + dz * dz);                \
    float rel = thr - d3;                                         \
    if ((JX) != t && rel > 0.0f) sep += rel;                      \
  }
    for (int g = 0; g < 64; ++g) {
      const float4 p0 = *(const float4*)&sh[g * 12];
      const float4 p1 = *(const float4*)&sh[g * 12 + 4];
      const float4 p2 = *(const float4*)&sh[g * 12 + 8];
      const float4 n0 = *(const float4*)&sh[768 + g * 12];
      const float4 n1 = *(const float4*)&sh[768 + g * 12 + 4];
      const float4 n2 = *(const float4*)&sh[768 + g * 12 + 8];
      const int j = g * 4;
      CHAM_STEP(j + 0, n0.x, n0.y, n0.z, p0.x, p0.y, p0.z);
      CHAM_STEP(j + 1, n0.w, n1.x, n1.y, p0.w, p1.x, p1.y);
      CHAM_STEP(j + 2, n1.z, n1.w, n2.x, p1.z, p1.w, p2.x);
      CHAM_STEP(j + 3, n2.y, n2.z, n2.w, p2.y, p2.z, p2.w);
    }
#undef CHAM_STEP
    float chf = sqrtf(fmaxf(m1, 1e-12f)) + sqrtf(fmaxf(m2, 1e-12f));
    chf = waveSum(chf);
    sep = waveSum(sep);
    if (lane == 0) { red[0][wave] = chf; red[1][wave] = sep; }
    __syncthreads();
    if (t == 0) {
      atomicAdd(&ws[0], red[0][0] + red[0][1] + red[0][2] + red[0][3]);
      atomicAdd(&ws[1], red[1][0] + red[1][1] + red[1][2] + red[1][3]);
    }

  } else if (bid < 640) {
    // ---------------- coverage per (b,k) ----------------
    const int bk = bid - 576;
    const int b = bk >> 1;
    const int k = bk & 1;
    float pmax0 = -1e9f, pmax1 = -1e9f, pmax2 = -1e9f;
    float pmin0 = 1e9f, pmin1 = 1e9f, pmin2 = 1e9f;
    const float* cb = cloud + (size_t)b * NCLOUD * 3;
    const int* lb = cls + (size_t)b * NCLOUD;
    for (int i = t; i < NCLOUD; i += 256) {
      if (lb[i] == k) {
        const float x = cb[i * 3 + 0], y = cb[i * 3 + 1], z = cb[i * 3 + 2];
        pmax0 = fmaxf(pmax0, x); pmax1 = fmaxf(pmax1, y); pmax2 = fmaxf(pmax2, z);
        pmin0 = fminf(pmin0, x); pmin1 = fminf(pmin1, y); pmin2 = fminf(pmin2, z);
      }
    }
    const float* nb = nodes + (size_t)bk * PP * 3;
    const float kx = nb[t * 3 + 0], ky = nb[t * 3 + 1], kz = nb[t * 3 + 2];
    pmax0 = waveMax(pmax0); pmax1 = waveMax(pmax1); pmax2 = waveMax(pmax2);
    pmin0 = waveMin(pmin0); pmin1 = waveMin(pmin1); pmin2 = waveMin(pmin2);
    float kmax0 = waveMax(kx), kmax1 = waveMax(ky), kmax2 = waveMax(kz);
    float kmin0 = waveMin(kx), kmin1 = waveMin(ky), kmin2 = waveMin(kz);
    if (lane == 0) {
      red[0][wave] = pmax0; red[1][wave] = pmax1; red[2][wave] = pmax2;
      red[3][wave] = pmin0; red[4][wave] = pmin1; red[5][wave] = pmin2;
      red[6][wave] = kmax0; red[7][wave] = kmax1; red[8][wave] = kmax2;
      red[9][wave] = kmin0; red[10][wave] = kmin1; red[11][wave] = kmin2;
    }
    __syncthreads();
    if (t == 0) {
      float v[12];
#pragma unroll
      for (int q = 0; q < 12; ++q) {
        if (q < 3 || (q >= 6 && q < 9))
          v[q] = fmaxf(fmaxf(red[q][0], red[q][1]), fmaxf(red[q][2], red[q][3]));
        else
          v[q] = fminf(fminf(red[q][0], red[q][1]), fminf(red[q][2], red[q][3]));
      }
      float s = 0.0f;
#pragma unroll
      for (int c2 = 0; c2 < 3; ++c2)
        s += 0.5f * (smooth_l1(v[6 + c2] - v[0 + c2]) + smooth_l1(v[9 + c2] - v[3 + c2]));
      atomicAdd(&ws[3], s);
    }

  } else if (bid < 704) {
    // ---------------- regularizer ----------------
    const int r = bid - 640;
    const float4* c4 = (const float4*)coefs;
    float v = 0.0f;
    for (int i = r * 256 + t; i < NCOEF / 4; i += 64 * 256) {
      const float4 q = c4[i];
      v += q.x * q.x + q.y * q.y + q.z * q.z + q.w * q.w;
    }
    v = waveSum(v);
    if (lane == 0) red[0][wave] = v;
    __syncthreads();
    if (t == 0)
      atomicAdd(&ws[6], red[0][0] + red[0][1] + red[0][2] + red[0][3]);

  } else {
    // ---------------- joint ----------------
    float cosv = 0.0f, locv = 0.0f;
    if (t < NB) {
      const float axj = pja[t * 3 + 0], ayj = pja[t * 3 + 1], azj = pja[t * 3 + 2];
      const float gx = gja[t * 3 + 0], gy = gja[t * 3 + 1], gz = gja[t * 3 + 2];
      const float dot = axj * gx + ayj * gy + azj * gz;
      const float na = sqrtf(axj * axj + ayj * ayj + azj * azj);
      const float nbn = sqrtf(gx * gx + gy * gy + gz * gz);
      cosv = dot / fmaxf(na * nbn, 1e-8f);
      const float ux = gx / nbn, uy = gy / nbn, uz = gz / nbn;
      const float px = gjl[t * 3 + 0], py = gjl[t * 3 + 1], pz = gjl[t * 3 + 2];
      const float qx = px + ux, qy = py + uy, qz = pz + uz;
      const float rx = pjl[t * 3 + 0], ry = pjl[t * 3 + 1], rz = pjl[t * 3 + 2];
      const float xx = px - qx, xy = py - qy, xz = pz - qz;
      const float tnum = (rx - qx) * xx + (ry - qy) * xy + (rz - qz) * xz;
      const float tden = xx * xx + xy * xy + xz * xz;
      const float tv = tnum / tden;
      const float vx = tv * xx + (qx - rx);
      const float vy = tv * xy + (qy - ry);
      const float vz = tv * xz + (qz - rz);
      locv = sqrtf(vx * vx + vy * vy + vz * vz);
    }
    cosv = waveSum(cosv);
    locv = waveSum(locv);
    if (t == 0) { atomicAdd(&ws[4], cosv); atomicAdd(&ws[5], locv); }
  }
}

// ---------------- final: reduce surf min-array + combine ----------------
__global__ __launch_bounds__(1024) void final_kernel(
    const float* __restrict__ ws, const unsigned int* __restrict__ minarr,
    float* __restrict__ out) {
  const int t = threadIdx.x;
  float s = 0.0f;
  for (int i = t; i < NB * NNODES; i += 1024)
    s += sqrtf(fmaxf(__uint_as_float(minarr[i]), 1e-12f));
  s = waveSum(s);
  __shared__ float r[16];
  const int wave = t >> 6, lane = t & 63;
  if (lane == 0) r[wave] = s;
  __syncthreads();
  if (t == 0) {
    float surf_sum = 0.0f;
#pragma unroll
    for (int q = 0; q < 16; ++q) surf_sum += r[q];
    const float chf = ws[0] / (float)(KK * NB * PP);
    const float sep = ws[1] / (float)(NB * KK * PP * (PP - 1));
    const float surf = surf_sum / (float)(NB * NNODES);
    const float cov = ws[3] / (float)(NB * KK * 3);
    const float axis = 1.0f - ws[4] / (float)NB;
    const float loc = ws[5] / (float)NB;
    const float reg = ws[6] / (float)NCOEF;
    out[0] = chf + cov + surf * 5.0f + (loc + 0.5f * axis) + reg * 0.01f + sep * 2.0f;
  }
}

extern "C" void kernel_launch(void* const* d_in, const int* in_sizes, int n_in,
                              void* d_out, int out_size, void* d_ws, size_t ws_size,
                              hipStream_t stream) {
  const float* coefs = (const float*)d_in[0];
  const float* preds = (const float*)d_in[1];
  const float* nodes = (const float*)d_in[2];
  const float* cloud = (const float*)d_in[3];
  const int* cls = (const int*)d_in[4];
  const float* pjl = (const float*)d_in[5];
  const float* pja = (const float*)d_in[6];
  const float* gjl = (const float*)d_in[7];
  const float* gja = (const float*)d_in[8];
  const float* gps = (const float*)d_in[9];
  float* out = (float*)d_out;
  float* ws = (float*)d_ws;
  unsigned int* minarr = (unsigned int*)(ws + 8);

  hipMemsetAsync(ws, 0, 8 * sizeof(float), stream);
  hipMemsetAsync(minarr, 0xFF, NB * NNODES * sizeof(unsigned int), stream);
  mega_kernel<<<705, 256, 0, stream>>>(coefs, preds, nodes, cloud, cls,
                                       pjl, pja, gjl, gja, gps, ws, minarr);
  final_kernel<<<1, 1024, 0, stream>>>(ws, minarr, out);
}